// Round 1
// baseline (15467.389 us; speedup 1.0000x reference)
//
#include <hip/hip_runtime.h>

#define T_LEN 4096
#define EMB   300
#define HD    256
#define G4    1024      // 4*HD (gate rows per direction)
#define N2    2048      // both directions
#define TAGS  12
#define NEGV  -10000.0f

// ---------------------------------------------------------------------------
// Kernel 1: g_in[t][dir*1024 + r] = embed[sent[t]] . W_ih_dir[r] + b_ih + b_hh
// Tiled f32 GEMM, M=4096 N=2048 K=300, 64x64 tiles, 256 thr, 4x4 per thread.
// ---------------------------------------------------------------------------
__global__ __launch_bounds__(256) void gin_gemm(
    const int* __restrict__ sent, const float* __restrict__ embed,
    const float* __restrict__ Wf, const float* __restrict__ Wb,
    const float* __restrict__ bihf, const float* __restrict__ bhhf,
    const float* __restrict__ bihb, const float* __restrict__ bhhb,
    float* __restrict__ gin)
{
    __shared__ float As[64][33];
    __shared__ float Bs[64][33];
    __shared__ int   sIdx[64];
    const int tid = threadIdx.x;
    const int bn = blockIdx.x;   // 0..31  (N tiles over 2048)
    const int bm = blockIdx.y;   // 0..63  (M tiles over 4096)
    if (tid < 64) sIdx[tid] = sent[bm*64 + tid];
    __syncthreads();

    float acc[4][4] = {};
    const int lr = tid >> 3;          // 0..31
    const int lk = (tid & 7) << 2;    // 0,4,..,28
    const int m0 = (tid >> 4) << 2;
    const int n0 = (tid & 15) << 2;

    for (int kc = 0; kc < 10; ++kc) {           // K chunks of 32 (covers 320, guard 300)
        const int k0 = kc*32 + lk;
        #pragma unroll
        for (int h = 0; h < 2; ++h) {
            const int row = lr + h*32;
            float4 va = make_float4(0.f,0.f,0.f,0.f);
            if (k0 + 3 < EMB)   // EMB % 4 == 0, so vectors are all-or-nothing
                va = *(const float4*)(embed + (long)sIdx[row]*EMB + k0);
            As[row][lk+0]=va.x; As[row][lk+1]=va.y; As[row][lk+2]=va.z; As[row][lk+3]=va.w;

            const int rn = bn*64 + row;          // tiles never straddle the 1024 boundary
            const float* bsrc = (rn < G4) ? (Wf + (long)rn*EMB) : (Wb + (long)(rn-G4)*EMB);
            float4 vb = make_float4(0.f,0.f,0.f,0.f);
            if (k0 + 3 < EMB)
                vb = *(const float4*)(bsrc + k0);
            Bs[row][lk+0]=vb.x; Bs[row][lk+1]=vb.y; Bs[row][lk+2]=vb.z; Bs[row][lk+3]=vb.w;
        }
        __syncthreads();
        #pragma unroll
        for (int kk = 0; kk < 32; ++kk) {
            float a[4], b[4];
            #pragma unroll
            for (int i = 0; i < 4; ++i) a[i] = As[m0+i][kk];
            #pragma unroll
            for (int i = 0; i < 4; ++i) b[i] = Bs[n0+i][kk];
            #pragma unroll
            for (int i = 0; i < 4; ++i)
                #pragma unroll
                for (int jj = 0; jj < 4; ++jj)
                    acc[i][jj] = fmaf(a[i], b[jj], acc[i][jj]);
        }
        __syncthreads();
    }

    #pragma unroll
    for (int i = 0; i < 4; ++i) {
        const int t = bm*64 + m0 + i;
        #pragma unroll
        for (int jj = 0; jj < 4; ++jj) {
            const int r = bn*64 + n0 + jj;
            const float bias = (r < G4) ? (bihf[r] + bhhf[r])
                                        : (bihb[r-G4] + bhhb[r-G4]);
            gin[(long)t*N2 + r] = acc[i][jj] + bias;
        }
    }
}

// ---------------------------------------------------------------------------
// Kernel 2: persistent BiLSTM recurrence.
// 8 blocks: block = dir*4 + wg.  Each block owns 64 hidden units of one
// direction; thread t owns gate row r = (t>>6)*256 + wg*64 + (t&63), with its
// 256 W_hh weights resident in VGPRs.  Per step: h broadcast via Hhist in
// global memory, agent-scope release/acquire flag sync between the 4 WGs of a
// direction.  c-state lives in registers of threads 0..63.
// ---------------------------------------------------------------------------
__global__ __launch_bounds__(256, 1) void lstm_persist(
    const float* __restrict__ Whhf, const float* __restrict__ Whhb,
    const float* __restrict__ h0, const float* __restrict__ c0,
    const float* __restrict__ gin, float* __restrict__ Hhist,
    int* __restrict__ flags)
{
    const int blk  = blockIdx.x;
    const int dir  = blk >> 2;
    const int wg   = blk & 3;
    const int tid  = threadIdx.x;
    const int j    = tid & 63;
    const int gate = tid >> 6;
    const int r    = gate*HD + wg*64 + j;

    const float4* wrow = (const float4*)((dir ? Whhb : Whhf) + (long)r*HD);
    float4 w[64];
    #pragma unroll
    for (int k = 0; k < 64; ++k) w[k] = wrow[k];   // weights persistent in VGPRs

    __shared__ __align__(16) float hS[HD];
    __shared__ float gv[4][64];

    float cst = (tid < 64) ? c0[dir*HD + wg*64 + j] : 0.f;

    #pragma unroll 1
    for (int s = 0; s < T_LEN; ++s) {
        const int t = dir ? (T_LEN-1-s) : s;
        const float gx = gin[(long)t*N2 + dir*G4 + r];   // prefetch (indep of flags)

        if (s > 0) {
            if (tid < 4) {
                while (__hip_atomic_load(&flags[(dir*4+tid)*16],
                                         __ATOMIC_ACQUIRE, __HIP_MEMORY_SCOPE_AGENT) < s) {}
            }
            __syncthreads();
            const int tp = dir ? (t+1) : (t-1);
            hS[tid] = Hhist[(long)tp*512 + dir*HD + tid];
        } else {
            hS[tid] = h0[dir*HD + tid];
        }
        __syncthreads();

        const float4* h4 = (const float4*)hS;     // uniform-address LDS reads (broadcast)
        float a0=0.f, a1=0.f, a2=0.f, a3=0.f;
        #pragma unroll
        for (int k = 0; k < 64; ++k) {
            const float4 hv = h4[k];
            a0 = fmaf(w[k].x, hv.x, a0);
            a1 = fmaf(w[k].y, hv.y, a1);
            a2 = fmaf(w[k].z, hv.z, a2);
            a3 = fmaf(w[k].w, hv.w, a3);
        }
        gv[gate][j] = gx + ((a0+a1)+(a2+a3));
        __syncthreads();

        if (tid < 64) {   // wave 0 finishes the unit update
            const float gi = gv[0][j], gf = gv[1][j], gg = gv[2][j], go = gv[3][j];
            const float i_ = 1.f/(1.f + expf(-gi));
            const float f_ = 1.f/(1.f + expf(-gf));
            const float g_ = tanhf(gg);
            const float o_ = 1.f/(1.f + expf(-go));
            cst = fmaf(f_, cst, i_*g_);
            const float hv = o_ * tanhf(cst);
            Hhist[(long)t*512 + dir*HD + wg*64 + j] = hv;
        }
        if (tid == 0) {   // release covers the whole wave-0 store above
            __hip_atomic_store(&flags[(dir*4+wg)*16], s+1,
                               __ATOMIC_RELEASE, __HIP_MEMORY_SCOPE_AGENT);
        }
    }
}

// ---------------------------------------------------------------------------
// Kernel 3: feats[t][tag] = [hf|hb][t] . W_tag[tag] + b_tag
// ---------------------------------------------------------------------------
__global__ __launch_bounds__(192) void feats_kernel(
    const float* __restrict__ Hhist, const float* __restrict__ Wtag,
    const float* __restrict__ btag, float* __restrict__ feats)
{
    __shared__ __align__(16) float Ws[TAGS][512];
    const int tid = threadIdx.x;
    for (int i = tid; i < TAGS*512; i += 192) Ws[0][i] = Wtag[i];
    __syncthreads();
    const int tl = tid / TAGS;            // 0..15
    const int tg = tid % TAGS;
    const int t  = blockIdx.x * 16 + tl;
    const float4* hrow = (const float4*)(Hhist + (long)t*512);
    const float4* wrow = (const float4*)(&Ws[tg][0]);
    float a0=0.f,a1=0.f,a2=0.f,a3=0.f;
    #pragma unroll 8
    for (int k = 0; k < 128; ++k) {
        const float4 h = hrow[k];
        const float4 ww = wrow[k];
        a0=fmaf(h.x,ww.x,a0); a1=fmaf(h.y,ww.y,a1);
        a2=fmaf(h.z,ww.z,a2); a3=fmaf(h.w,ww.w,a3);
    }
    feats[t*TAGS + tg] = ((a0+a1)+(a2+a3)) + btag[tg];
}

// ---------------------------------------------------------------------------
// Kernel 4: Viterbi forward scan (12 lanes of wave 0) + serial backtrack.
// bps kept in LDS (48 KB).  out[0] = score, out[1..4096] = path as floats.
// ---------------------------------------------------------------------------
__global__ __launch_bounds__(256) void viterbi_kernel(
    const float* __restrict__ feats, const float* __restrict__ trans,
    float* __restrict__ out)
{
    __shared__ float fS[256*TAGS];                 // 12 KB feats chunk
    __shared__ unsigned char bps[T_LEN*TAGS];      // 48 KB backpointers
    __shared__ float fvS[TAGS];
    const int tid = threadIdx.x;

    float tr[TAGS];
    float fv = NEGV;
    if (tid < TAGS) {
        #pragma unroll
        for (int f = 0; f < TAGS; ++f) tr[f] = trans[tid*TAGS + f];
        fv = (tid == 10) ? 0.f : NEGV;             // START = 10
    }

    for (int c = 0; c < T_LEN/256; ++c) {
        __syncthreads();
        for (int i = tid; i < 256*TAGS; i += 256) fS[i] = feats[c*256*TAGS + i];
        __syncthreads();
        if (tid < TAGS) {
            for (int s = 0; s < 256; ++s) {
                float best = -3.4e38f; int bp = 0;
                #pragma unroll
                for (int f = 0; f < TAGS; ++f) {
                    const float v = __shfl(fv, f, 64) + tr[f];
                    if (v > best) { best = v; bp = f; }   // strict > keeps first max (np semantics)
                }
                bps[(c*256+s)*TAGS + tid] = (unsigned char)bp;
                fv = best + fS[s*TAGS + tid];
            }
        }
    }
    __syncthreads();
    if (tid < TAGS) fvS[tid] = fv + trans[11*TAGS + tid];  // STOP = 11
    __syncthreads();
    if (tid == 0) {
        float bestv = fvS[0]; int best = 0;
        #pragma unroll
        for (int g = 1; g < TAGS; ++g) if (fvS[g] > bestv) { bestv = fvS[g]; best = g; }
        out[0] = bestv;
        int cur = best;
        for (int t = T_LEN-1; t >= 0; --t) {
            out[1+t] = (float)cur;
            cur = bps[t*TAGS + cur];
        }
    }
}

// ---------------------------------------------------------------------------
// Host launch.  ws layout (floats):
//   gin   [4096*2048]          = 33.5 MB
//   Hhist [4096*512]           =  8.4 MB
//   feats [4096*12]            =  0.2 MB
//   flags [8 * 16 ints]        (64B-strided flags; memset each call)
// Total ~42.2 MB of d_ws.
// ---------------------------------------------------------------------------
extern "C" void kernel_launch(void* const* d_in, const int* in_sizes, int n_in,
                              void* d_out, int out_size, void* d_ws, size_t ws_size,
                              hipStream_t stream)
{
    (void)in_sizes; (void)n_in; (void)out_size; (void)ws_size;
    const int*   sentence = (const int*)  d_in[0];
    const float* h0       = (const float*)d_in[1];
    const float* c0       = (const float*)d_in[2];
    const float* embed    = (const float*)d_in[3];
    const float* Wihf     = (const float*)d_in[4];
    const float* Whhf     = (const float*)d_in[5];
    const float* bihf     = (const float*)d_in[6];
    const float* bhhf     = (const float*)d_in[7];
    const float* Wihb     = (const float*)d_in[8];
    const float* Whhb     = (const float*)d_in[9];
    const float* bihb     = (const float*)d_in[10];
    const float* bhhb     = (const float*)d_in[11];
    const float* Wtag     = (const float*)d_in[12];
    const float* btag     = (const float*)d_in[13];
    const float* trans    = (const float*)d_in[14];
    float* out = (float*)d_out;

    float* gin   = (float*)d_ws;
    float* Hhist = gin   + (long)T_LEN*N2;
    float* feats = Hhist + (long)T_LEN*512;
    int*   flags = (int*)(feats + (long)T_LEN*TAGS);

    hipMemsetAsync(flags, 0, 8*16*sizeof(int), stream);

    dim3 ggrid(32, 64);
    gin_gemm<<<ggrid, 256, 0, stream>>>(sentence, embed, Wihf, Wihb,
                                        bihf, bhhf, bihb, bhhb, gin);
    lstm_persist<<<8, 256, 0, stream>>>(Whhf, Whhb, h0, c0, gin, Hhist, flags);
    feats_kernel<<<T_LEN/16, 192, 0, stream>>>(Hhist, Wtag, btag, feats);
    viterbi_kernel<<<1, 256, 0, stream>>>(feats, trans, out);
}